// Round 12
// baseline (436.750 us; speedup 1.0000x reference)
//
#include <hip/hip_runtime.h>
#include <math.h>

typedef unsigned short u16;
typedef unsigned int   u32;
typedef short bf8v __attribute__((ext_vector_type(8)));   // 8 bf16 in 4 VGPRs
typedef float f4v  __attribute__((ext_vector_type(4)));

static constexpr int B_=4, C_=256, K_=5, D_=256, N_=4096, IT_=4;
static constexpr int LP_=264;   // padded LDS row stride (u16)
static constexpr float EPS_=1e-5f;
static constexpr int NB_BASE=1024;
static constexpr int NB_Q0=1024;    // +20
static constexpr int NB_WQ=1044;    // +256
static constexpr int NB_WR=1300;    // +256
static constexpr int NB_WIH=1556;   // +768
static constexpr int NB_WHH=2324;   // +768
static constexpr int NB_UQ=3092;    // +1
static constexpr int NB_FG=3093;    // +5
static constexpr int NB_TOT=3098;

__device__ __forceinline__ float bf2f(u16 u){ u32 x=((u32)u)<<16; float f; __builtin_memcpy(&f,&x,4); return f; }
__device__ __forceinline__ float bflo(u32 u){ u32 x=u<<16; float f; __builtin_memcpy(&f,&x,4); return f; }
__device__ __forceinline__ float bfhi(u32 u){ u32 x=u&0xffff0000u; float f; __builtin_memcpy(&f,&x,4); return f; }
__device__ __forceinline__ u16 f2bf(float f){ u32 x; __builtin_memcpy(&x,&f,4); u32 r=x+0x7fffu+((x>>16)&1u); return (u16)(r>>16); }
__device__ __forceinline__ float ldin(const void* p, size_t i, int f){
  return f ? ((const float*)p)[i] : bf2f(((const u16*)p)[i]);
}
__device__ __forceinline__ void stout(void* p, size_t i, float v, int f){
  if (f) ((float*)p)[i]=v; else ((u16*)p)[i]=f2bf(v);
}
__device__ __forceinline__ bf8v loadW8(const void* p, size_t i, int f){
  if(!f) return *(const bf8v*)((const u16*)p + i);
  float4 a=*(const float4*)((const float*)p+i);
  float4 b=*(const float4*)((const float*)p+i+4);
  bf8v r;
  r[0]=(short)f2bf(a.x); r[1]=(short)f2bf(a.y); r[2]=(short)f2bf(a.z); r[3]=(short)f2bf(a.w);
  r[4]=(short)f2bf(b.x); r[5]=(short)f2bf(b.y); r[6]=(short)f2bf(b.z); r[7]=(short)f2bf(b.w);
  return r;
}

__device__ __forceinline__ void breduce4(float&a,float&b,float&c,float&d,float* red){
  #pragma unroll
  for(int o=32;o>0;o>>=1){
    a+=__shfl_down(a,o,64); b+=__shfl_down(b,o,64);
    c+=__shfl_down(c,o,64); d+=__shfl_down(d,o,64);
  }
  int w=threadIdx.x>>6;
  __syncthreads();
  if((threadIdx.x&63)==0){ red[w]=a; red[4+w]=b; red[8+w]=c; red[12+w]=d; }
  __syncthreads();
  a=red[0]+red[1]+red[2]+red[3];
  b=red[4]+red[5]+red[6]+red[7];
  c=red[8]+red[9]+red[10]+red[11];
  d=red[12]+red[13]+red[14]+red[15];
}
__device__ __forceinline__ void breduce4_16(float&a,float&b,float&c,float&d,float* red){
  #pragma unroll
  for(int o=32;o>0;o>>=1){
    a+=__shfl_down(a,o,64); b+=__shfl_down(b,o,64);
    c+=__shfl_down(c,o,64); d+=__shfl_down(d,o,64);
  }
  int w=threadIdx.x>>6;
  __syncthreads();
  if((threadIdx.x&63)==0){ red[w]=a; red[16+w]=b; red[32+w]=c; red[48+w]=d; }
  __syncthreads();
  a=0;b=0;c=0;d=0;
  #pragma unroll
  for(int i=0;i<16;++i){ a+=red[i]; b+=red[16+i]; c+=red[32+i]; d+=red[48+i]; }
}

// ==== setup: probe inline; base | slot+q0 | transposes | uq | fgpos ====
__global__ void __launch_bounds__(256) setup_kernel(const void* feat,
    const void* kW, const void* vW, const void* mW, const void* qW, const void* rW,
    const void* Wih, const void* Whh, const void* mu, const void* lsig, const void* noise,
    const void* gW, const void* gb_, const void* mg, const void* mb_, const void* mbias,
    const void* ng, const void* nb, const void* qg, const void* qb_, const void* mask,
    int* flag, float* WqT, float* WrT, float* WihT, float* WhhT,
    float* slot, float* Uvec, float* Qs, float* fg,
    float* scal, u16* PkT, u16* Pvb, float* qbuf, void* out)
{
  __shared__ u16 fnb[16*LP_];
  __shared__ u16 kbL[16*LP_];
  __shared__ u16 vbL[16*LP_];
  __shared__ float redp[16];
  int t=threadIdx.x, bid=blockIdx.x;
  int f;
  {
    const u32* pf=(const u32*)feat;
    int bad=0;
    #pragma unroll
    for(int s=0;s<8;++s){
      u32 wd=pf[t+s*256];
      float lo=bf2f((u16)(wd&0xffffu));
      if(!(fabsf(lo)<1e6f)) bad++;
    }
    float bb=(float)bad, z1=0,z2=0,z3=0;
    breduce4(bb,z1,z2,z3,redp);
    f=(bb>=16.f)?1:0;
    if(bid==NB_Q0 && t==0) *flag=f;
  }
  __syncthreads();

  if(bid>=NB_BASE){
    if(bid<NB_WQ){
      // ---- slot init + iter-0 q projection ----
      float* Lq=(float*)fnb; float* red=(float*)vbL;
      int bk=bid-NB_Q0;
      float x=ldin(mu,t,f)+expf(ldin(lsig,t,f))*ldin(noise,(size_t)bk*256+t,f);
      slot[bk*256+t]=x;
      float s=x,s2=x*x,z0=0,z1=0; breduce4(s,s2,z0,z1,red);
      float m=s*(1.f/256.f), v=s2*(1.f/256.f)-m*m;
      Lq[t]=(x-m)*rsqrtf(v+EPS_)*ldin(qg,t,f)+ldin(qb_,t,f);
      __syncthreads();
      float acc=0;
      if(!f){
        const u16* qr=(const u16*)qW + (size_t)t*256;
        #pragma unroll 8
        for(int c0=0;c0<256;c0+=8){
          uint4 u=*(const uint4*)(qr+c0);
          acc+=bflo(u.x)*Lq[c0]+bfhi(u.x)*Lq[c0+1]+bflo(u.y)*Lq[c0+2]+bfhi(u.y)*Lq[c0+3]
              +bflo(u.z)*Lq[c0+4]+bfhi(u.z)*Lq[c0+5]+bflo(u.w)*Lq[c0+6]+bfhi(u.w)*Lq[c0+7];
        }
      }else{
        const float* qr=(const float*)qW + (size_t)t*256;
        #pragma unroll 8
        for(int c=0;c<256;++c) acc+=qr[c]*Lq[c];
      }
      qbuf[bk*256+t]=acc;
      return;
    }
    if(bid<NB_WR){ int e=(bid-NB_WQ)*256+t; int c=e>>8, r=e&255; WqT[e]=ldin(qW,(size_t)r*256+c,f); return; }
    if(bid<NB_WIH){ int e=(bid-NB_WR)*256+t; int c=e>>8, r=e&255; WrT[e]=ldin(rW,(size_t)r*256+c,f); return; }
    if(bid<NB_WHH){ int e=(bid-NB_WIH)*256+t; int c=e/768, r=e-c*768; WihT[e]=ldin(Wih,(size_t)r*256+c,f); return; }
    if(bid<NB_UQ){ int e=(bid-NB_WHH)*256+t; int c=e/768, r=e-c*768; WhhT[e]=ldin(Whh,(size_t)r*256+c,f); return; }
    if(bid==NB_UQ){
      float* s_a=(float*)fnb; float* s_b=(float*)kbL; float* s_c=(float*)vbL;
      s_a[t]=ldin(gW,t*4+0,f)-ldin(gW,t*4+2,f);
      s_b[t]=ldin(gW,t*4+1,f)-ldin(gW,t*4+3,f);
      s_c[t]=ldin(gb_,t,f);
      __syncthreads();
      float u1=0,u2=0,u3=0,gw=0,bw=0;
      #pragma unroll 8
      for(int c=0;c<256;++c){
        float mwv=ldin(mW,(size_t)t*256+c,f);
        float wg=ldin(mg,c,f)*mwv;
        u1+=s_a[c]*wg; u2+=s_b[c]*wg; u3+=s_c[c]*wg; gw+=wg;
        bw+=ldin(mb_,c,f)*mwv;
      }
      Uvec[t]=u1; Uvec[256+t]=u2; Uvec[512+t]=u3; Uvec[768+t]=gw;
      Uvec[1024+t]=bw+ldin(mbias,t,f);
      float a=s_a[t], b=s_b[t], cc=s_c[t];
      float s0=a*a,s1=b*b,s2=cc*cc,s3=a*b; breduce4(s0,s1,s2,s3,redp);
      float s4=a*cc,s5=b*cc,s6=a,s7=b;     breduce4(s4,s5,s6,s7,redp);
      float s8=cc,z1=0,z2=0,z3=0;          breduce4(s8,z1,z2,z3,redp);
      if(t==0){
        Qs[0]=s0; Qs[1]=s1; Qs[2]=s2; Qs[3]=s3; Qs[4]=s4; Qs[5]=s5;
        Qs[6]=s6*(1.f/256.f); Qs[7]=s7*(1.f/256.f); Qs[8]=s8*(1.f/256.f);
      }
      return;
    }
    {
      int k=bid-NB_FG;
      float sx=0,sy=0,sm=0;
      for(int s=0;s<16;++s){
        int p=t+s*256;
        float m=ldin(mask,(size_t)k*N_+p,f);
        int i=p>>6, j=p&63;
        float x=(2*j+1)*(1.0f/64.0f)-1.0f;
        float y=(2*i+1)*(1.0f/64.0f)-1.0f;
        sx+=x*m; sy+=y*m; sm+=m;
      }
      float d=0;
      breduce4(sx,sy,sm,d,redp);
      if(t==0){
        float inv=1.0f/(sm+1e-5f);
        float fx=sx*inv, fy=sy*inv;
        fg[k*2]=fx; fg[k*2+1]=fy;
        for(int b=0;b<B_;++b){
          stout(out, 5120+(b*K_+k)*2+0, fx, f);
          stout(out, 5120+(b*K_+k)*2+1, fy, f);
        }
      }
      return;
    }
  }

  // ======== base path ========
  int w=t>>6, l=t&63;
  int quad=l>>4, m=l&15;
  int row0=bid*16;
  {
    float g0=ldin(ng,l,f), g1=ldin(ng,l+64,f), g2=ldin(ng,l+128,f), g3=ldin(ng,l+192,f);
    float b0=ldin(nb,l,f), b1=ldin(nb,l+64,f), b2=ldin(nb,l+128,f), b3=ldin(nb,l+192,f);
    #pragma unroll
    for(int r4=0;r4<4;++r4){
      int r=4*w+r4; size_t base=(size_t)(row0+r)*256;
      float x0=ldin(feat,base+l,f), x1=ldin(feat,base+l+64,f),
            x2=ldin(feat,base+l+128,f), x3=ldin(feat,base+l+192,f);
      float s=x0+x1+x2+x3, s2=x0*x0+x1*x1+x2*x2+x3*x3;
      #pragma unroll
      for(int o=32;o>0;o>>=1){ s+=__shfl_xor(s,o,64); s2+=__shfl_xor(s2,o,64); }
      float mm=s*(1.f/256.f), inv=rsqrtf(s2*(1.f/256.f)-mm*mm+EPS_);
      fnb[r*LP_+l]    =f2bf((x0-mm)*inv*g0+b0);
      fnb[r*LP_+l+64] =f2bf((x1-mm)*inv*g1+b1);
      fnb[r*LP_+l+128]=f2bf((x2-mm)*inv*g2+b2);
      fnb[r*LP_+l+192]=f2bf((x3-mm)*inv*g3+b3);
    }
  }
  __syncthreads();
  // pass1: kb/vb = fn @ {kW,vW}^T (raw weights)
  {
    f4v ack[4], acv[4];
    #pragma unroll
    for(int i=0;i<4;++i){ ack[i]=(f4v){0.f,0.f,0.f,0.f}; acv[i]=(f4v){0.f,0.f,0.f,0.f}; }
    #pragma unroll
    for(int kk=0;kk<8;++kk){
      int kb0=kk*32+quad*8;
      bf8v af=*(bf8v*)&fnb[m*LP_+kb0];
      #pragma unroll
      for(int i=0;i<4;++i){
        int n=64*w+16*i+m;
        bf8v bk=loadW8(kW,(size_t)n*256+kb0,f);
        bf8v bv=loadW8(vW,(size_t)n*256+kb0,f);
        ack[i]=__builtin_amdgcn_mfma_f32_16x16x32_bf16(af,bk,ack[i],0,0,0);
        acv[i]=__builtin_amdgcn_mfma_f32_16x16x32_bf16(af,bv,acv[i],0,0,0);
      }
    }
    #pragma unroll
    for(int i=0;i<4;++i){
      int n=64*w+16*i+m;
      #pragma unroll
      for(int r=0;r<4;++r){
        int row=quad*4+r;
        kbL[row*LP_+n]=f2bf(ack[i][r]);
        vbL[row*LP_+n]=f2bf(acv[i][r]);
      }
    }
  }
  __syncthreads();
  // per-row scalars (gvec inlined from gW/gb)
  {
    float gA0=ldin(gW,l*4+0,f)-ldin(gW,l*4+2,f);
    float gA1=ldin(gW,(l+64)*4+0,f)-ldin(gW,(l+64)*4+2,f);
    float gA2=ldin(gW,(l+128)*4+0,f)-ldin(gW,(l+128)*4+2,f);
    float gA3=ldin(gW,(l+192)*4+0,f)-ldin(gW,(l+192)*4+2,f);
    float gB0=ldin(gW,l*4+1,f)-ldin(gW,l*4+3,f);
    float gB1=ldin(gW,(l+64)*4+1,f)-ldin(gW,(l+64)*4+3,f);
    float gB2=ldin(gW,(l+128)*4+1,f)-ldin(gW,(l+128)*4+3,f);
    float gB3=ldin(gW,(l+192)*4+1,f)-ldin(gW,(l+192)*4+3,f);
    float gC0=ldin(gb_,l,f), gC1=ldin(gb_,l+64,f), gC2=ldin(gb_,l+128,f), gC3=ldin(gb_,l+192,f);
    for(int r4=0;r4<4;++r4){
      int r=4*w+r4;
      float k0=bf2f(kbL[r*LP_+l]), k1=bf2f(kbL[r*LP_+l+64]),
            k2=bf2f(kbL[r*LP_+l+128]), k3=bf2f(kbL[r*LP_+l+192]);
      float x0=bf2f(vbL[r*LP_+l]), x1=bf2f(vbL[r*LP_+l+64]),
            x2=bf2f(vbL[r*LP_+l+128]), x3=bf2f(vbL[r*LP_+l+192]);
      float v0=k0+k1+k2+k3;
      float v1=k0*k0+k1*k1+k2*k2+k3*k3;
      float v2=k0*gA0+k1*gA1+k2*gA2+k3*gA3;
      float v3=k0*gB0+k1*gB1+k2*gB2+k3*gB3;
      float v4=k0*gC0+k1*gC1+k2*gC2+k3*gC3;
      float v5=x0+x1+x2+x3;
      float v6=x0*x0+x1*x1+x2*x2+x3*x3;
      float v7=x0*gA0+x1*gA1+x2*gA2+x3*gA3;
      float v8=x0*gB0+x1*gB1+x2*gB2+x3*gB3;
      float v9=x0*gC0+x1*gC1+x2*gC2+x3*gC3;
      #pragma unroll
      for(int o=32;o>0;o>>=1){
        v0+=__shfl_down(v0,o,64); v1+=__shfl_down(v1,o,64); v2+=__shfl_down(v2,o,64);
        v3+=__shfl_down(v3,o,64); v4+=__shfl_down(v4,o,64); v5+=__shfl_down(v5,o,64);
        v6+=__shfl_down(v6,o,64); v7+=__shfl_down(v7,o,64); v8+=__shfl_down(v8,o,64);
        v9+=__shfl_down(v9,o,64);
      }
      if(l==0){
        float* sc=scal+(size_t)(row0+r)*10;
        sc[0]=v0; sc[1]=v1; sc[2]=v2; sc[3]=v3; sc[4]=v4;
        sc[5]=v5; sc[6]=v6; sc[7]=v7; sc[8]=v8; sc[9]=v9;
      }
    }
  }
  // pass2: Pk/Pv = (kb·mg)/( vb·mg) @ mW^T  (mg applied on A-fragment)
  {
    f4v apk[4], apv[4];
    #pragma unroll
    for(int i=0;i<4;++i){ apk[i]=(f4v){0.f,0.f,0.f,0.f}; apv[i]=(f4v){0.f,0.f,0.f,0.f}; }
    #pragma unroll
    for(int kk=0;kk<8;++kk){
      int kb0=kk*32+quad*8;
      bf8v rk=*(bf8v*)&kbL[m*LP_+kb0];
      bf8v rv=*(bf8v*)&vbL[m*LP_+kb0];
      bf8v afk, afv;
      #pragma unroll
      for(int j=0;j<8;++j){
        float mgv=ldin(mg,kb0+j,f);
        afk[j]=(short)f2bf(bf2f((u16)rk[j])*mgv);
        afv[j]=(short)f2bf(bf2f((u16)rv[j])*mgv);
      }
      #pragma unroll
      for(int i=0;i<4;++i){
        int n=64*w+16*i+m;
        bf8v bg=loadW8(mW,(size_t)n*256+kb0,f);
        apk[i]=__builtin_amdgcn_mfma_f32_16x16x32_bf16(afk,bg,apk[i],0,0,0);
        apv[i]=__builtin_amdgcn_mfma_f32_16x16x32_bf16(afv,bg,apv[i],0,0,0);
      }
    }
    #pragma unroll
    for(int i=0;i<4;++i){
      int d=64*w+16*i+m;
      *(ushort4*)(PkT+(size_t)d*16384+row0+quad*4)=
        make_ushort4(f2bf(apk[i][0]),f2bf(apk[i][1]),f2bf(apk[i][2]),f2bf(apk[i][3]));
      #pragma unroll
      for(int r=0;r<4;++r)
        fnb[(quad*4+r)*LP_+d]=f2bf(apv[i][r]);
    }
  }
  __syncthreads();
  {
    int d0=l*4;
    #pragma unroll
    for(int r=0;r<4;++r){
      int row=4*w+r;
      ushort4 s4=make_ushort4(fnb[row*LP_+d0],fnb[row*LP_+d0+1],fnb[row*LP_+d0+2],fnb[row*LP_+d0+3]);
      *(ushort4*)(Pvb+(size_t)(row0+row)*256+d0)=s4;
    }
  }
}

// ---- fused attn (512 threads): qsc inline + logits + chunk softmax + weighted Pv partials ----
__global__ void __launch_bounds__(512) attn_kernel(const int* flag, const float* qbuf, const u16* PkT,
    const float* scal, const float* Qs, const float* Uvec, const float* fg, const void* mask,
    const u16* Pvb, float* logits, float* pmax, float* psum, float* updpart, float* sscp,
    int store_lg)
{
  __shared__ float q5[1280];
  __shared__ float un[10240];
  __shared__ float lgs[320], ivs[320], mvs[320];
  __shared__ float qs5[40], fgs[10], Qss[9], MSl[5];
  __shared__ float sred[8][5][4];
  int tid=threadIdx.x, f=*flag;
  int b=blockIdx.x>>6, ch=blockIdx.x&63;
  int w=tid>>6, l=tid&63;
  int n0=ch<<6;
  for(int p=tid;p<1280;p+=512) q5[p]=qbuf[(size_t)b*1280+p];
  if(tid<10) fgs[tid]=fg[tid];
  if(tid<9)  Qss[tid]=Qs[tid];
  __syncthreads();
  // qsc inline: pairs (k,j), dot of q5[k] with Uvec[j]
  for(int p=w;p<25;p+=8){
    int k=p/5, j=p%5;
    float s=q5[k*256+l]*Uvec[j*256+l]+q5[k*256+l+64]*Uvec[j*256+l+64]
           +q5[k*256+l+128]*Uvec[j*256+l+128]+q5[k*256+l+192]*Uvec[j*256+l+192];
    #pragma unroll
    for(int o=32;o>0;o>>=1) s+=__shfl_xor(s,o,64);
    if(l==0) qs5[k*8+j]=s;
  }
  // dots
  {
    int n=n0+l; size_t row=(size_t)b*N_+n;
    float dk0=0,dk1=0,dk2=0,dk3=0,dk4=0;
    int cbase=w*32;
    #pragma unroll 8
    for(int cc=0;cc<32;++cc){
      int c=cbase+cc;
      float pv=bf2f(PkT[(size_t)c*16384+row]);
      dk0+=pv*q5[c]; dk1+=pv*q5[256+c]; dk2+=pv*q5[512+c];
      dk3+=pv*q5[768+c]; dk4+=pv*q5[1024+c];
    }
    un[(w*5+0)*64+l]=dk0; un[(w*5+1)*64+l]=dk1; un[(w*5+2)*64+l]=dk2;
    un[(w*5+3)*64+l]=dk3; un[(w*5+4)*64+l]=dk4;
  }
  __syncthreads();
  if(tid<320){
    int k=tid>>6, nl=tid&63;
    float dot=0;
    #pragma unroll
    for(int j=0;j<8;++j) dot+=un[(j*5+k)*64+nl];
    int n2=n0+nl; size_t row2=(size_t)b*N_+n2;
    const float* sc=scal+row2*10;
    float rx=(2*(n2&63)+1)*(1.f/64.f)-1.f-fgs[2*k];
    float ry=(2*(n2>>6)+1)*(1.f/64.f)-1.f-fgs[2*k+1];
    float qge=rx*rx*Qss[0]+ry*ry*Qss[1]+Qss[2]+2.f*(rx*ry*Qss[3]+rx*Qss[4]+ry*Qss[5]);
    float mk=sc[0]*(1.f/256.f)+rx*Qss[6]+ry*Qss[7]+Qss[8];
    float sxk=sc[1]+2.f*(rx*sc[2]+ry*sc[3]+sc[4])+qge;
    float invK=rsqrtf(sxk*(1.f/256.f)-mk*mk+EPS_);
    float lg=invK*(dot+rx*qs5[k*8+0]+ry*qs5[k*8+1]+qs5[k*8+2]-mk*qs5[k*8+3])+qs5[k*8+4];
    float mval=ldin(mask,(size_t)k*N_+n2,f);
    lg=(mval==0.f)? -1e9f : lg*0.0625f;
    if(store_lg) logits[((size_t)(b*5+k))*N_+n2]=lg;
    lgs[tid]=lg;
    float mv=sc[5]*(1.f/256.f)+rx*Qss[6]+ry*Qss[7]+Qss[8];
    float sxv=sc[6]+2.f*(rx*sc[7]+ry*sc[8]+sc[9])+qge;
    mvs[tid]=mv;
    ivs[tid]=rsqrtf(sxv*(1.f/256.f)-mv*mv+EPS_);
  }
  __syncthreads();
  if(tid<64){
    #pragma unroll
    for(int k=0;k<5;++k){
      float v=lgs[k*64+tid];
      float M=v;
      #pragma unroll
      for(int o=32;o>0;o>>=1) M=fmaxf(M,__shfl_xor(M,o,64));
      float e=expf(v-M);
      #pragma unroll
      for(int o=32;o>0;o>>=1) e+=__shfl_xor(e,o,64);
      if(tid==0){ pmax[((size_t)(b*64+ch))*5+k]=M; psum[((size_t)(b*64+ch))*5+k]=e; MSl[k]=M; }
    }
  }
  __syncthreads();
  {
    float acc[5][4]={{0}};
    float swx[5]={0,0,0,0,0}, swy[5]={0,0,0,0,0}, sw[5]={0,0,0,0,0}, swm[5]={0,0,0,0,0};
    #pragma unroll 2
    for(int rr=0;rr<8;++rr){
      int nl=w*8+rr; int n2=n0+nl;
      size_t row=(size_t)b*N_+n2;
      uint2 pu=*(const uint2*)(Pvb+row*256+l*4);
      float px=bflo(pu.x), py=bfhi(pu.x), pz=bflo(pu.y), pw=bfhi(pu.y);
      int jx=n2&63, iy=n2>>6;
      #pragma unroll
      for(int k=0;k<5;++k){
        float wgt=expf(lgs[k*64+nl]-MSl[k])*ivs[k*64+nl];
        float rx=(2*jx+1)*(1.f/64.f)-1.f-fgs[2*k];
        float ry=(2*iy+1)*(1.f/64.f)-1.f-fgs[2*k+1];
        acc[k][0]+=wgt*px; acc[k][1]+=wgt*py; acc[k][2]+=wgt*pz; acc[k][3]+=wgt*pw;
        sw[k]+=wgt; swx[k]+=wgt*rx; swy[k]+=wgt*ry; swm[k]+=wgt*mvs[k*64+nl];
      }
    }
    #pragma unroll
    for(int k=0;k<5;++k)
      *(float4*)&un[(w*5+k)*256+l*4]=make_float4(acc[k][0],acc[k][1],acc[k][2],acc[k][3]);
    if(l==0){
      #pragma unroll
      for(int k=0;k<5;++k){ sred[w][k][0]=swx[k]; sred[w][k][1]=swy[k];
                            sred[w][k][2]=sw[k];  sred[w][k][3]=swm[k]; }
    }
  }
  __syncthreads();
  for(int p=tid;p<1280;p+=512){
    int k=p>>8, d=p&255;
    float v=0;
    #pragma unroll
    for(int j=0;j<8;++j) v+=un[(j*5+k)*256+d];
    updpart[((size_t)blockIdx.x*5+k)*256+d]=v;
  }
  if(tid<20){
    int kk=tid>>2, j=tid&3;
    float s=0;
    #pragma unroll
    for(int jj=0;jj<8;++jj) s+=sred[jj][kk][j];
    sscp[((size_t)blockIdx.x*5+kk)*4+j]=s;
  }
}

// ---- GRU (blocks 0..19) + optional vis (blocks 20..39 when do_vis) ----
__global__ void __launch_bounds__(1024) gru_kernel(const int* flag, float* slot, const float* updpart,
    const float* sscp, const float* Uvec, const float* pmax, const float* psum, const float* logits,
    const float* WihT, const float* WhhT, const void* bih, const void* bhh,
    const void* rg, const void* rb_, const float* WrT, const void* rbias,
    const void* qg, const void* qb_, const float* WqT, float* qbuf,
    int do_vis, void* out)
{
  __shared__ float u[256], h[256], sn[256];
  __shared__ float part[4][6][256];
  __shared__ float red[64];
  __shared__ float cvec[4];
  __shared__ float fch[64];
  __shared__ float MSg[2];
  int tid=threadIdx.x, t=tid&255, g=tid>>8;
  int blk=blockIdx.x;
  int f=*flag;
  if(blk>=20){
    if(!do_vis) return;
    int bk2=blk-20, k2=bk2%K_, b2=bk2/K_;
    if(tid<64){
      float pm=pmax[((size_t)(b2*64+tid))*5+k2];
      float ps=psum[((size_t)(b2*64+tid))*5+k2];
      float M=pm;
      #pragma unroll
      for(int o=32;o>0;o>>=1) M=fmaxf(M,__shfl_xor(M,o,64));
      float e=ps*expf(pm-M);
      #pragma unroll
      for(int o=32;o>0;o>>=1) e+=__shfl_xor(e,o,64);
      if(tid==0){ MSg[0]=M; MSg[1]=1.0f/e; }
    }
    __syncthreads();
    float M=MSg[0], Sinv=MSg[1];
    float a[4]; float mn=1e30f, mx=-1e30f;
    #pragma unroll
    for(int s=0;s<4;++s){
      a[s]=expf(logits[(size_t)bk2*N_+tid+s*1024]-M)*Sinv;
      mn=fminf(mn,a[s]); mx=fmaxf(mx,a[s]);
    }
    #pragma unroll
    for(int o=32;o>0;o>>=1){ mn=fminf(mn,__shfl_down(mn,o,64)); mx=fmaxf(mx,__shfl_down(mx,o,64)); }
    int wv=tid>>6;
    __syncthreads();
    if((tid&63)==0){ red[wv]=mn; red[16+wv]=mx; }
    __syncthreads();
    mn=1e30f; mx=-1e30f;
    #pragma unroll
    for(int i=0;i<16;++i){ mn=fminf(mn,red[i]); mx=fmaxf(mx,red[16+i]); }
    float inv=1.0f/(mx-mn+1e-5f);
    #pragma unroll
    for(int s=0;s<4;++s) stout(out, 5160+(size_t)bk2*N_+tid+s*1024, (a[s]-mn)*inv, f);
    return;
  }
  int bk=blk, k=bk%K_, b=bk/K_;
  if(tid<64){
    float pm=pmax[((size_t)(b*64+tid))*5+k];
    float ps=psum[((size_t)(b*64+tid))*5+k];
    float M=pm;
    #pragma unroll
    for(int o=32;o>0;o>>=1) M=fmaxf(M,__shfl_xor(M,o,64));
    float fc=expf(pm-M);
    fch[tid]=fc;
    float e=ps*fc;
    #pragma unroll
    for(int o=32;o>0;o>>=1) e+=__shfl_xor(e,o,64);
    if(tid==0){ MSg[0]=M; MSg[1]=1.0f/e; }
  }
  __syncthreads();
  float Sinv=MSg[1];
  float ua=0;
  {
    int ch0=g*16;
    #pragma unroll 4
    for(int ci=0;ci<16;++ci){ int ch=ch0+ci; ua += fch[ch]*updpart[(((size_t)(b*64+ch))*5+k)*256+t]; }
  }
  part[g][0][t]=ua;
  if(t<4){
    float s=0;
    #pragma unroll 4
    for(int ci=0;ci<16;++ci){ int ch=g*16+ci; s += fch[ch]*sscp[(((size_t)(b*64+ch))*5+k)*4+t]; }
    part[g][1][t]=s;
  }
  __syncthreads();
  if(g==0 && t<4) cvec[t]=part[0][1][t]+part[1][1][t]+part[2][1][t]+part[3][1][t];
  __syncthreads();
  if(g==0){
    float uu=part[0][0][t]+part[1][0][t]+part[2][0][t]+part[3][0][t];
    u[t]=(uu+cvec[0]*Uvec[t]+cvec[1]*Uvec[256+t]+cvec[2]*Uvec[512+t]-cvec[3]*Uvec[768+t])*Sinv
         +Uvec[1024+t];
    h[t]=slot[bk*256+t];
  }
  __syncthreads();
  float p0=0,p1=0,p2=0,p3=0,p4=0,p5=0;
  int c0=g*64;
  #pragma unroll 8
  for(int cc=0;cc<64;++cc){
    int c=c0+cc;
    float uc=u[c], hc=h[c];
    const float* wi=WihT+(size_t)c*768+t;
    const float* wh=WhhT+(size_t)c*768+t;
    p0+=uc*wi[0]; p1+=uc*wi[256]; p2+=uc*wi[512];
    p3+=hc*wh[0]; p4+=hc*wh[256]; p5+=hc*wh[512];
  }
  part[g][0][t]=p0; part[g][1][t]=p1; part[g][2][t]=p2;
  part[g][3][t]=p3; part[g][4][t]=p4; part[g][5][t]=p5;
  __syncthreads();
  float hn=0;
  if(g==0){
    float gi0=ldin(bih,t,f)+part[0][0][t]+part[1][0][t]+part[2][0][t]+part[3][0][t];
    float gi1=ldin(bih,256+t,f)+part[0][1][t]+part[1][1][t]+part[2][1][t]+part[3][1][t];
    float gi2=ldin(bih,512+t,f)+part[0][2][t]+part[1][2][t]+part[2][2][t]+part[3][2][t];
    float gh0=ldin(bhh,t,f)+part[0][3][t]+part[1][3][t]+part[2][3][t]+part[3][3][t];
    float gh1=ldin(bhh,256+t,f)+part[0][4][t]+part[1][4][t]+part[2][4][t]+part[3][4][t];
    float gh2=ldin(bhh,512+t,f)+part[0][5][t]+part[1][5][t]+part[2][5][t]+part[3][5][t];
    float r=1.f/(1.f+expf(-(gi0+gh0)));
    float z=1.f/(1.f+expf(-(gi1+gh1)));
    float nn=tanhf(gi2+r*gh2);
    hn=(1.f-z)*nn+z*h[t];
  }
  float s=hn, sq=hn*hn, za=0, zb=0;
  breduce4_16(s,sq,za,zb,red);
  if(g==0){
    float m=s*(1.f/256.f), var=sq*(1.f/256.f)-m*m;
    u[t]=(hn-m)*rsqrtf(var+EPS_)*ldin(rg,t,f)+ldin(rb_,t,f);
  }
  __syncthreads();
  float pr=0;
  #pragma unroll 8
  for(int cc=0;cc<64;++cc){ int c=c0+cc; pr+=u[c]*WrT[(size_t)c*256+t]; }
  part[g][0][t]=pr;
  __syncthreads();
  if(g==0){
    float acc=ldin(rbias,t,f)+h[t]+part[0][0][t]+part[1][0][t]+part[2][0][t]+part[3][0][t];
    slot[bk*256+t]=acc;
    stout(out, (size_t)bk*256+t, acc, f);
    sn[t]=acc;
  }
  __syncthreads();
  float xs=(g==0)? sn[t]:0.f;
  float xq=xs*xs, zc=0, zd=0;
  breduce4_16(xs,xq,zc,zd,red);
  if(g==0){
    float m=xs*(1.f/256.f), var=xq*(1.f/256.f)-m*m;
    u[t]=(sn[t]-m)*rsqrtf(var+EPS_)*ldin(qg,t,f)+ldin(qb_,t,f);
  }
  __syncthreads();
  float pq=0;
  #pragma unroll 8
  for(int cc=0;cc<64;++cc){ int c=c0+cc; pq+=u[c]*WqT[(size_t)c*256+t]; }
  part[g][0][t]=pq;
  __syncthreads();
  if(g==0){
    float qv=part[0][0][t]+part[1][0][t]+part[2][0][t]+part[3][0][t];
    qbuf[bk*256+t]=qv;
  }
}

extern "C" void kernel_launch(void* const* d_in, const int* in_sizes, int n_in,
                              void* d_out, int out_size, void* d_ws, size_t ws_size,
                              hipStream_t stream)
{
  const void* feat =d_in[0];  const void* mask =d_in[1];  const void* noise=d_in[2];
  const void* mu   =d_in[3];  const void* lsig =d_in[4];  const void* ng   =d_in[5];
  const void* nb   =d_in[6];  const void* gW   =d_in[7];  const void* gb_  =d_in[8];
  const void* kW   =d_in[9];  const void* vW   =d_in[10]; const void* mg   =d_in[11];
  const void* mb_  =d_in[12]; const void* mW   =d_in[13]; const void* mbias=d_in[14];
  const void* qg   =d_in[15]; const void* qb_  =d_in[16]; const void* qW   =d_in[17];
  const void* Wih  =d_in[18]; const void* Whh  =d_in[19]; const void* bih  =d_in[20];
  const void* bhh  =d_in[21]; const void* rg   =d_in[22]; const void* rb_  =d_in[23];
  const void* rW   =d_in[24]; const void* rbias=d_in[25];

  char* p=(char*)d_ws;
  auto alloc=[&](size_t bytes)->char*{ char* r=p; p+=(bytes+255)&~(size_t)255; return r; };
  int*   flag   =(int*)  alloc(256);
  float* fg     =(float*)alloc(64);
  float* slot   =(float*)alloc(5120*4);
  float* qbuf   =(float*)alloc(5120*4);
  float* logits =(float*)alloc((size_t)81920*4);
  float* pmax   =(float*)alloc(1280*4);
  float* psum   =(float*)alloc(1280*4);
  float* updpart=(float*)alloc((size_t)256*5*256*4);
  float* sscp   =(float*)alloc((size_t)256*5*4*4);
  float* WqT    =(float*)alloc((size_t)65536*4);
  float* WrT    =(float*)alloc((size_t)65536*4);
  float* WihT   =(float*)alloc((size_t)196608*4);
  float* WhhT   =(float*)alloc((size_t)196608*4);
  float* Uvec   =(float*)alloc(1280*4);
  float* Qs     =(float*)alloc(64);
  float* scal   =(float*)alloc((size_t)163840*4);
  u16*   PkT    =(u16*)  alloc((size_t)16384*256*2);
  u16*   Pvb    =(u16*)  alloc((size_t)16384*256*2);

  setup_kernel<<<NB_TOT,256,0,stream>>>(feat,kW,vW,mW,qW,rW,Wih,Whh,mu,lsig,noise,
                                        gW,gb_,mg,mb_,mbias,ng,nb,qg,qb_,mask,
                                        flag,WqT,WrT,WihT,WhhT,slot,Uvec,Qs,fg,
                                        scal,PkT,Pvb,qbuf,d_out);
  for(int it=0; it<IT_; ++it){
    attn_kernel<<<B_*64,512,0,stream>>>(flag,qbuf,PkT,scal,Qs,Uvec,fg,mask,Pvb,
                                        logits,pmax,psum,updpart,sscp,(it==IT_-1)?1:0);
    int nb_g = (it==IT_-1)? 40 : 20;
    gru_kernel<<<nb_g,1024,0,stream>>>(flag,slot,updpart,sscp,Uvec,pmax,psum,logits,
                                       WihT,WhhT,bih,bhh,rg,rb_,WrT,rbias,
                                       qg,qb_,WqT,qbuf,(it==IT_-1)?1:0,d_out);
  }
}

// Round 13
// 383.042 us; speedup vs baseline: 1.1402x; 1.1402x over previous
//
#include <hip/hip_runtime.h>
#include <math.h>

typedef unsigned short u16;
typedef unsigned int   u32;
typedef short bf8v __attribute__((ext_vector_type(8)));   // 8 bf16 in 4 VGPRs
typedef float f4v  __attribute__((ext_vector_type(4)));

static constexpr int B_=4, C_=256, K_=5, D_=256, N_=4096, IT_=4;
static constexpr int LP_=264;      // padded LDS row stride (u16)
static constexpr int PREP_N=2839;  // prep transpose blocks; +6 for uq/fgpos
static constexpr float EPS_=1e-5f;

__device__ __forceinline__ float bf2f(u16 u){ u32 x=((u32)u)<<16; float f; __builtin_memcpy(&f,&x,4); return f; }
__device__ __forceinline__ float bflo(u32 u){ u32 x=u<<16; float f; __builtin_memcpy(&f,&x,4); return f; }
__device__ __forceinline__ float bfhi(u32 u){ u32 x=u&0xffff0000u; float f; __builtin_memcpy(&f,&x,4); return f; }
__device__ __forceinline__ u16 f2bf(float f){ u32 x; __builtin_memcpy(&x,&f,4); u32 r=x+0x7fffu+((x>>16)&1u); return (u16)(r>>16); }
__device__ __forceinline__ float ldin(const void* p, size_t i, int f){
  return f ? ((const float*)p)[i] : bf2f(((const u16*)p)[i]);
}
__device__ __forceinline__ void stout(void* p, size_t i, float v, int f){
  if (f) ((float*)p)[i]=v; else ((u16*)p)[i]=f2bf(v);
}

// ---- 256-thread (4-wave) reductions ----
__device__ __forceinline__ void breduce4(float&a,float&b,float&c,float&d,float* red){
  #pragma unroll
  for(int o=32;o>0;o>>=1){
    a+=__shfl_down(a,o,64); b+=__shfl_down(b,o,64);
    c+=__shfl_down(c,o,64); d+=__shfl_down(d,o,64);
  }
  int w=threadIdx.x>>6;
  __syncthreads();
  if((threadIdx.x&63)==0){ red[w]=a; red[4+w]=b; red[8+w]=c; red[12+w]=d; }
  __syncthreads();
  a=red[0]+red[1]+red[2]+red[3];
  b=red[4]+red[5]+red[6]+red[7];
  c=red[8]+red[9]+red[10]+red[11];
  d=red[12]+red[13]+red[14]+red[15];
}
// ---- 1024-thread (16-wave) reduction ----
__device__ __forceinline__ void breduce4_16(float&a,float&b,float&c,float&d,float* red){
  #pragma unroll
  for(int o=32;o>0;o>>=1){
    a+=__shfl_down(a,o,64); b+=__shfl_down(b,o,64);
    c+=__shfl_down(c,o,64); d+=__shfl_down(d,o,64);
  }
  int w=threadIdx.x>>6;
  __syncthreads();
  if((threadIdx.x&63)==0){ red[w]=a; red[16+w]=b; red[32+w]=c; red[48+w]=d; }
  __syncthreads();
  a=0;b=0;c=0;d=0;
  #pragma unroll
  for(int i=0;i<16;++i){ a+=red[i]; b+=red[16+i]; c+=red[32+i]; d+=red[48+i]; }
}

// ---- inline dtype probe (feat head is LLC-hot; ~8KB shared across blocks) ----
__device__ __forceinline__ int probe_f(const void* feat, float* red){
  const u32* p=(const u32*)feat;
  int t=threadIdx.x; int bad=0;
  #pragma unroll
  for(int s=0;s<8;++s){
    u32 wd=p[t+s*256];
    float lo=bf2f((u16)(wd&0xffffu));
    if(!(fabsf(lo)<1e6f)) bad++;
  }
  float bb=(float)bad, z1=0,z2=0,z3=0;
  breduce4(bb,z1,z2,z3,red);
  return (bb>=16.f)?1:0;
}

// ---- prep (blocks 0..PREP_N-1): coalesced-output transposes + slot init + gvec + bf16 weights
// ---- block PREP_N: uq;  PREP_N+1..PREP_N+5: fgpos.  Probe inline; block 0 publishes flag.
__global__ void prep1_kernel(const void* feat,
    const void* kW, const void* vW, const void* mW, const void* qW, const void* rW,
    const void* Wih, const void* Whh, const void* mu, const void* lsig, const void* noise,
    const void* gW, const void* gb_, const void* mg,
    const void* mb_, const void* mbias, const void* mask,
    int* flag, float* WqT, float* WrT, float* WihT, float* WhhT,
    float* slot, float* gvec,
    u16* Wkb, u16* Wvb, u16* Wgb,
    float* Uvec, float* Qs, float* fg, void* out)
{
  __shared__ float redp[16];
  int bid=blockIdx.x;
  int t=threadIdx.x;
  int f=probe_f(feat, redp);
  if(bid==0 && t==0) *flag=f;
  __syncthreads();
  if(bid<PREP_N){
    int e=bid*256+t;
    if(e<65536){ int c=e>>8, r=e&255; WqT[e]=ldin(qW,(size_t)r*256+c,f); return;} e-=65536;
    if(e<65536){ int c=e>>8, r=e&255; WrT[e]=ldin(rW,(size_t)r*256+c,f); return;} e-=65536;
    if(e<196608){ int c=e/768, r=e-c*768; WihT[e]=ldin(Wih,(size_t)r*256+c,f); return;} e-=196608;
    if(e<196608){ int c=e/768, r=e-c*768; WhhT[e]=ldin(Whh,(size_t)r*256+c,f); return;} e-=196608;
    if(e<5120){ int d=e&255; slot[e]=ldin(mu,d,f)+expf(ldin(lsig,d,f))*ldin(noise,e,f); return;} e-=5120;
    if(e<768){
      int c=e&255, sel=e>>8;
      float v;
      if(sel==0)      v=ldin(gW,c*4+0,f)-ldin(gW,c*4+2,f);
      else if(sel==1) v=ldin(gW,c*4+1,f)-ldin(gW,c*4+3,f);
      else            v=ldin(gb_,c,f);
      gvec[e]=v; return;
    } e-=768;
    if(e<65536){ Wkb[e]=f2bf(ldin(kW,e,f)); return;} e-=65536;
    if(e<65536){ Wvb[e]=f2bf(ldin(vW,e,f)); return;} e-=65536;
    if(e<65536){ int c=e&255; Wgb[e]=f2bf(ldin(mg,c,f)*ldin(mW,e,f)); }
    return;
  }
  __shared__ float s_a[256], s_b[256], s_c[256];
  if(bid==PREP_N){
    s_a[t]=ldin(gW,t*4+0,f)-ldin(gW,t*4+2,f);
    s_b[t]=ldin(gW,t*4+1,f)-ldin(gW,t*4+3,f);
    s_c[t]=ldin(gb_,t,f);
    __syncthreads();
    float u1=0,u2=0,u3=0,gw=0,bw=0;
    #pragma unroll 8
    for(int c=0;c<256;++c){
      float mwv=ldin(mW,(size_t)t*256+c,f);
      float wg=ldin(mg,c,f)*mwv;
      u1+=s_a[c]*wg; u2+=s_b[c]*wg; u3+=s_c[c]*wg; gw+=wg;
      bw+=ldin(mb_,c,f)*mwv;
    }
    Uvec[t]=u1; Uvec[256+t]=u2; Uvec[512+t]=u3; Uvec[768+t]=gw;
    Uvec[1024+t]=bw+ldin(mbias,t,f);
    float a=s_a[t], b=s_b[t], cc=s_c[t];
    float s0=a*a,s1=b*b,s2=cc*cc,s3=a*b; breduce4(s0,s1,s2,s3,redp);
    float s4=a*cc,s5=b*cc,s6=a,s7=b;     breduce4(s4,s5,s6,s7,redp);
    float s8=cc,z1=0,z2=0,z3=0;          breduce4(s8,z1,z2,z3,redp);
    if(t==0){
      Qs[0]=s0; Qs[1]=s1; Qs[2]=s2; Qs[3]=s3; Qs[4]=s4; Qs[5]=s5;
      Qs[6]=s6*(1.f/256.f); Qs[7]=s7*(1.f/256.f); Qs[8]=s8*(1.f/256.f);
    }
  } else {
    int k=bid-PREP_N-1;
    float sx=0,sy=0,sm=0;
    for(int s=0;s<16;++s){
      int p=t+s*256;
      float m=ldin(mask,(size_t)k*N_+p,f);
      int i=p>>6, j=p&63;
      float x=(2*j+1)*(1.0f/64.0f)-1.0f;
      float y=(2*i+1)*(1.0f/64.0f)-1.0f;
      sx+=x*m; sy+=y*m; sm+=m;
    }
    float d=0;
    breduce4(sx,sy,sm,d,redp);
    if(t==0){
      float inv=1.0f/(sm+1e-5f);
      float fx=sx*inv, fy=sy*inv;
      fg[k*2]=fx; fg[k*2+1]=fy;
      for(int b=0;b<B_;++b){
        stout(out, 5120+(b*K_+k)*2+0, fx, f);
        stout(out, 5120+(b*K_+k)*2+1, fy, f);
      }
    }
  }
}

// ---- base (blocks 0..1023): LN -> fnb(bf16) -> MFMA pass1 -> kbL/vbL -> scalars + MFMA pass2
// ---- blocks 1024..1043: iter-0 q projection (no qsc — attn computes it inline)
__global__ void __launch_bounds__(256) base_kernel(const int* flag, const void* feat, const void* ng, const void* nb,
    const u16* Wkb, const u16* Wvb, const u16* Wgb, const float* gvec,
    float* scal, u16* PkT, u16* Pvb,
    const float* slot, const void* qg, const void* qb_, const float* WqT,
    float* qbuf)
{
  __shared__ u16 fnb[16*LP_];
  __shared__ u16 kbL[16*LP_];
  __shared__ u16 vbL[16*LP_];
  int t=threadIdx.x, f=*flag;
  if(blockIdx.x>=1024){
    float* Lq=(float*)fnb; float* red=(float*)vbL;
    int bk=blockIdx.x-1024;
    float x=slot[bk*256+t];
    float s=x,s2=x*x,z0=0,z1=0; breduce4(s,s2,z0,z1,red);
    float m=s*(1.f/256.f), v=s2*(1.f/256.f)-m*m;
    Lq[t]=(x-m)*rsqrtf(v+EPS_)*ldin(qg,t,f)+ldin(qb_,t,f);
    __syncthreads();
    float acc=0;
    #pragma unroll 8
    for(int c=0;c<256;++c) acc+=Lq[c]*WqT[c*256+t];
    qbuf[bk*256+t]=acc;
    return;
  }
  int w=t>>6, l=t&63;
  int quad=l>>4, m=l&15;
  int row0=blockIdx.x*16;
  {
    float g0=ldin(ng,l,f), g1=ldin(ng,l+64,f), g2=ldin(ng,l+128,f), g3=ldin(ng,l+192,f);
    float b0=ldin(nb,l,f), b1=ldin(nb,l+64,f), b2=ldin(nb,l+128,f), b3=ldin(nb,l+192,f);
    #pragma unroll
    for(int r4=0;r4<4;++r4){
      int r=4*w+r4; size_t base=(size_t)(row0+r)*256;
      float x0=ldin(feat,base+l,f), x1=ldin(feat,base+l+64,f),
            x2=ldin(feat,base+l+128,f), x3=ldin(feat,base+l+192,f);
      float s=x0+x1+x2+x3, s2=x0*x0+x1*x1+x2*x2+x3*x3;
      #pragma unroll
      for(int o=32;o>0;o>>=1){ s+=__shfl_xor(s,o,64); s2+=__shfl_xor(s2,o,64); }
      float mm=s*(1.f/256.f), inv=rsqrtf(s2*(1.f/256.f)-mm*mm+EPS_);
      fnb[r*LP_+l]    =f2bf((x0-mm)*inv*g0+b0);
      fnb[r*LP_+l+64] =f2bf((x1-mm)*inv*g1+b1);
      fnb[r*LP_+l+128]=f2bf((x2-mm)*inv*g2+b2);
      fnb[r*LP_+l+192]=f2bf((x3-mm)*inv*g3+b3);
    }
  }
  __syncthreads();
  {
    f4v ack[4], acv[4];
    #pragma unroll
    for(int i=0;i<4;++i){ ack[i]=(f4v){0.f,0.f,0.f,0.f}; acv[i]=(f4v){0.f,0.f,0.f,0.f}; }
    #pragma unroll
    for(int kk=0;kk<8;++kk){
      int kb0=kk*32+quad*8;
      bf8v af=*(bf8v*)&fnb[m*LP_+kb0];
      #pragma unroll
      for(int i=0;i<4;++i){
        int n=64*w+16*i+m;
        bf8v bk=*(const bf8v*)(Wkb+(size_t)n*256+kb0);
        bf8v bv=*(const bf8v*)(Wvb+(size_t)n*256+kb0);
        ack[i]=__builtin_amdgcn_mfma_f32_16x16x32_bf16(af,bk,ack[i],0,0,0);
        acv[i]=__builtin_amdgcn_mfma_f32_16x16x32_bf16(af,bv,acv[i],0,0,0);
      }
    }
    #pragma unroll
    for(int i=0;i<4;++i){
      int n=64*w+16*i+m;
      #pragma unroll
      for(int r=0;r<4;++r){
        int row=quad*4+r;
        kbL[row*LP_+n]=f2bf(ack[i][r]);
        vbL[row*LP_+n]=f2bf(acv[i][r]);
      }
    }
  }
  __syncthreads();
  {
    float gA0=gvec[l], gA1=gvec[l+64], gA2=gvec[l+128], gA3=gvec[l+192];
    float gB0=gvec[256+l], gB1=gvec[256+l+64], gB2=gvec[256+l+128], gB3=gvec[256+l+192];
    float gC0=gvec[512+l], gC1=gvec[512+l+64], gC2=gvec[512+l+128], gC3=gvec[512+l+192];
    for(int r4=0;r4<4;++r4){
      int r=4*w+r4;
      float k0=bf2f(kbL[r*LP_+l]), k1=bf2f(kbL[r*LP_+l+64]),
            k2=bf2f(kbL[r*LP_+l+128]), k3=bf2f(kbL[r*LP_+l+192]);
      float x0=bf2f(vbL[r*LP_+l]), x1=bf2f(vbL[r*LP_+l+64]),
            x2=bf2f(vbL[r*LP_+l+128]), x3=bf2f(vbL[r*LP_+l+192]);
      float v0=k0+k1+k2+k3;
      float v1=k0*k0+k1*k1+k2*k2+k3*k3;
      float v2=k0*gA0+k1*gA1+k2*gA2+k3*gA3;
      float v3=k0*gB0+k1*gB1+k2*gB2+k3*gB3;
      float v4=k0*gC0+k1*gC1+k2*gC2+k3*gC3;
      float v5=x0+x1+x2+x3;
      float v6=x0*x0+x1*x1+x2*x2+x3*x3;
      float v7=x0*gA0+x1*gA1+x2*gA2+x3*gA3;
      float v8=x0*gB0+x1*gB1+x2*gB2+x3*gB3;
      float v9=x0*gC0+x1*gC1+x2*gC2+x3*gC3;
      #pragma unroll
      for(int o=32;o>0;o>>=1){
        v0+=__shfl_down(v0,o,64); v1+=__shfl_down(v1,o,64); v2+=__shfl_down(v2,o,64);
        v3+=__shfl_down(v3,o,64); v4+=__shfl_down(v4,o,64); v5+=__shfl_down(v5,o,64);
        v6+=__shfl_down(v6,o,64); v7+=__shfl_down(v7,o,64); v8+=__shfl_down(v8,o,64);
        v9+=__shfl_down(v9,o,64);
      }
      if(l==0){
        float* sc=scal+(size_t)(row0+r)*10;
        sc[0]=v0; sc[1]=v1; sc[2]=v2; sc[3]=v3; sc[4]=v4;
        sc[5]=v5; sc[6]=v6; sc[7]=v7; sc[8]=v8; sc[9]=v9;
      }
    }
  }
  {
    f4v apk[4], apv[4];
    #pragma unroll
    for(int i=0;i<4;++i){ apk[i]=(f4v){0.f,0.f,0.f,0.f}; apv[i]=(f4v){0.f,0.f,0.f,0.f}; }
    #pragma unroll
    for(int kk=0;kk<8;++kk){
      int kb0=kk*32+quad*8;
      bf8v afk=*(bf8v*)&kbL[m*LP_+kb0];
      bf8v afv=*(bf8v*)&vbL[m*LP_+kb0];
      #pragma unroll
      for(int i=0;i<4;++i){
        int n=64*w+16*i+m;
        bf8v bg=*(const bf8v*)(Wgb+(size_t)n*256+kb0);
        apk[i]=__builtin_amdgcn_mfma_f32_16x16x32_bf16(afk,bg,apk[i],0,0,0);
        apv[i]=__builtin_amdgcn_mfma_f32_16x16x32_bf16(afv,bg,apv[i],0,0,0);
      }
    }
    #pragma unroll
    for(int i=0;i<4;++i){
      int d=64*w+16*i+m;
      *(ushort4*)(PkT+(size_t)d*16384+row0+quad*4)=
        make_ushort4(f2bf(apk[i][0]),f2bf(apk[i][1]),f2bf(apk[i][2]),f2bf(apk[i][3]));
      #pragma unroll
      for(int r=0;r<4;++r)
        fnb[(quad*4+r)*LP_+d]=f2bf(apv[i][r]);
    }
  }
  __syncthreads();
  {
    int d0=l*4;
    #pragma unroll
    for(int r=0;r<4;++r){
      int row=4*w+r;
      ushort4 s4=make_ushort4(fnb[row*LP_+d0],fnb[row*LP_+d0+1],fnb[row*LP_+d0+2],fnb[row*LP_+d0+3]);
      *(ushort4*)(Pvb+(size_t)(row0+row)*256+d0)=s4;
    }
  }
}

// ---- fused attn (512 threads): qsc inline + logits + chunk softmax + weighted Pv partials ----
__global__ void __launch_bounds__(512) attn_kernel(const int* flag, const float* qbuf, const u16* PkT,
    const float* scal, const float* Qs, const float* Uvec, const float* fg, const void* mask,
    const u16* Pvb, float* logits, float* pmax, float* psum, float* updpart, float* sscp,
    int store_lg)
{
  __shared__ float q5[1280];
  __shared__ float un[10240];
  __shared__ float lgs[320], ivs[320], mvs[320];
  __shared__ float qs5[40], fgs[10], Qss[9], MSl[5];
  __shared__ float sred[8][5][4];
  int tid=threadIdx.x, f=*flag;
  int b=blockIdx.x>>6, ch=blockIdx.x&63;
  int w=tid>>6, l=tid&63;
  int n0=ch<<6;
  for(int p=tid;p<1280;p+=512) q5[p]=qbuf[(size_t)b*1280+p];
  if(tid<10) fgs[tid]=fg[tid];
  if(tid<9)  Qss[tid]=Qs[tid];
  __syncthreads();
  // qsc inline
  for(int p=w;p<25;p+=8){
    int k=p/5, j=p%5;
    float s=q5[k*256+l]*Uvec[j*256+l]+q5[k*256+l+64]*Uvec[j*256+l+64]
           +q5[k*256+l+128]*Uvec[j*256+l+128]+q5[k*256+l+192]*Uvec[j*256+l+192];
    #pragma unroll
    for(int o=32;o>0;o>>=1) s+=__shfl_xor(s,o,64);
    if(l==0) qs5[k*8+j]=s;
  }
  {
    int n=n0+l; size_t row=(size_t)b*N_+n;
    float dk0=0,dk1=0,dk2=0,dk3=0,dk4=0;
    int cbase=w*32;
    #pragma unroll 8
    for(int cc=0;cc<32;++cc){
      int c=cbase+cc;
      float pv=bf2f(PkT[(size_t)c*16384+row]);
      dk0+=pv*q5[c]; dk1+=pv*q5[256+c]; dk2+=pv*q5[512+c];
      dk3+=pv*q5[768+c]; dk4+=pv*q5[1024+c];
    }
    un[(w*5+0)*64+l]=dk0; un[(w*5+1)*64+l]=dk1; un[(w*5+2)*64+l]=dk2;
    un[(w*5+3)*64+l]=dk3; un[(w*5+4)*64+l]=dk4;
  }
  __syncthreads();
  if(tid<320){
    int k=tid>>6, nl=tid&63;
    float dot=0;
    #pragma unroll
    for(int j=0;j<8;++j) dot+=un[(j*5+k)*64+nl];
    int n2=n0+nl; size_t row2=(size_t)b*N_+n2;
    const float* sc=scal+row2*10;
    float rx=(2*(n2&63)+1)*(1.f/64.f)-1.f-fgs[2*k];
    float ry=(2*(n2>>6)+1)*(1.f/64.f)-1.f-fgs[2*k+1];
    float qge=rx*rx*Qss[0]+ry*ry*Qss[1]+Qss[2]+2.f*(rx*ry*Qss[3]+rx*Qss[4]+ry*Qss[5]);
    float mk=sc[0]*(1.f/256.f)+rx*Qss[6]+ry*Qss[7]+Qss[8];
    float sxk=sc[1]+2.f*(rx*sc[2]+ry*sc[3]+sc[4])+qge;
    float invK=rsqrtf(sxk*(1.f/256.f)-mk*mk+EPS_);
    float lg=invK*(dot+rx*qs5[k*8+0]+ry*qs5[k*8+1]+qs5[k*8+2]-mk*qs5[k*8+3])+qs5[k*8+4];
    float mval=ldin(mask,(size_t)k*N_+n2,f);
    lg=(mval==0.f)? -1e9f : lg*0.0625f;
    if(store_lg) logits[((size_t)(b*5+k))*N_+n2]=lg;
    lgs[tid]=lg;
    float mv=sc[5]*(1.f/256.f)+rx*Qss[6]+ry*Qss[7]+Qss[8];
    float sxv=sc[6]+2.f*(rx*sc[7]+ry*sc[8]+sc[9])+qge;
    mvs[tid]=mv;
    ivs[tid]=rsqrtf(sxv*(1.f/256.f)-mv*mv+EPS_);
  }
  __syncthreads();
  if(tid<64){
    #pragma unroll
    for(int k=0;k<5;++k){
      float v=lgs[k*64+tid];
      float M=v;
      #pragma unroll
      for(int o=32;o>0;o>>=1) M=fmaxf(M,__shfl_xor(M,o,64));
      float e=expf(v-M);
      #pragma unroll
      for(int o=32;o>0;o>>=1) e+=__shfl_xor(e,o,64);
      if(tid==0){ pmax[((size_t)(b*64+ch))*5+k]=M; psum[((size_t)(b*64+ch))*5+k]=e; MSl[k]=M; }
    }
  }
  __syncthreads();
  {
    float acc[5][4]={{0}};
    float swx[5]={0,0,0,0,0}, swy[5]={0,0,0,0,0}, sw[5]={0,0,0,0,0}, swm[5]={0,0,0,0,0};
    #pragma unroll 2
    for(int rr=0;rr<8;++rr){
      int nl=w*8+rr; int n2=n0+nl;
      size_t row=(size_t)b*N_+n2;
      uint2 pu=*(const uint2*)(Pvb+row*256+l*4);
      float px=bflo(pu.x), py=bfhi(pu.x), pz=bflo(pu.y), pw=bfhi(pu.y);
      int jx=n2&63, iy=n2>>6;
      #pragma unroll
      for(int k=0;k<5;++k){
        float wgt=expf(lgs[k*64+nl]-MSl[k])*ivs[k*64+nl];
        float rx=(2*jx+1)*(1.f/64.f)-1.f-fgs[2*k];
        float ry=(2*iy+1)*(1.f/64.f)-1.f-fgs[2*k+1];
        acc[k][0]+=wgt*px; acc[k][1]+=wgt*py; acc[k][2]+=wgt*pz; acc[k][3]+=wgt*pw;
        sw[k]+=wgt; swx[k]+=wgt*rx; swy[k]+=wgt*ry; swm[k]+=wgt*mvs[k*64+nl];
      }
    }
    #pragma unroll
    for(int k=0;k<5;++k)
      *(float4*)&un[(w*5+k)*256+l*4]=make_float4(acc[k][0],acc[k][1],acc[k][2],acc[k][3]);
    if(l==0){
      #pragma unroll
      for(int k=0;k<5;++k){ sred[w][k][0]=swx[k]; sred[w][k][1]=swy[k];
                            sred[w][k][2]=sw[k];  sred[w][k][3]=swm[k]; }
    }
  }
  __syncthreads();
  for(int p=tid;p<1280;p+=512){
    int k=p>>8, d=p&255;
    float v=0;
    #pragma unroll
    for(int j=0;j<8;++j) v+=un[(j*5+k)*256+d];
    updpart[((size_t)blockIdx.x*5+k)*256+d]=v;
  }
  if(tid<20){
    int kk=tid>>2, j=tid&3;
    float s=0;
    #pragma unroll
    for(int jj=0;jj<8;++jj) s+=sred[jj][kk][j];
    sscp[((size_t)blockIdx.x*5+kk)*4+j]=s;
  }
}

// ---- GRU (blocks 0..19) + optional vis (blocks 20..39 when do_vis) ----
__global__ void __launch_bounds__(1024) gru_kernel(const int* flag, float* slot, const float* updpart,
    const float* sscp, const float* Uvec, const float* pmax, const float* psum, const float* logits,
    const float* WihT, const float* WhhT, const void* bih, const void* bhh,
    const void* rg, const void* rb_, const float* WrT, const void* rbias,
    const void* qg, const void* qb_, const float* WqT, float* qbuf,
    int do_vis, void* out)
{
  __shared__ float u[256], h[256], sn[256];
  __shared__ float part[4][6][256];
  __shared__ float red[64];
  __shared__ float cvec[4];
  __shared__ float fch[64];
  __shared__ float MSg[2];
  int tid=threadIdx.x, t=tid&255, g=tid>>8;
  int blk=blockIdx.x;
  int f=*flag;
  if(blk>=20){
    if(!do_vis) return;
    int bk2=blk-20, k2=bk2%K_, b2=bk2/K_;
    if(tid<64){
      float pm=pmax[((size_t)(b2*64+tid))*5+k2];
      float ps=psum[((size_t)(b2*64+tid))*5+k2];
      float M=pm;
      #pragma unroll
      for(int o=32;o>0;o>>=1) M=fmaxf(M,__shfl_xor(M,o,64));
      float e=ps*expf(pm-M);
      #pragma unroll
      for(int o=32;o>0;o>>=1) e+=__shfl_xor(e,o,64);
      if(tid==0){ MSg[0]=M; MSg[1]=1.0f/e; }
    }
    __syncthreads();
    float M=MSg[0], Sinv=MSg[1];
    float a[4]; float mn=1e30f, mx=-1e30f;
    #pragma unroll
    for(int s=0;s<4;++s){
      a[s]=expf(logits[(size_t)bk2*N_+tid+s*1024]-M)*Sinv;
      mn=fminf(mn,a[s]); mx=fmaxf(mx,a[s]);
    }
    #pragma unroll
    for(int o=32;o>0;o>>=1){ mn=fminf(mn,__shfl_down(mn,o,64)); mx=fmaxf(mx,__shfl_down(mx,o,64)); }
    int wv=tid>>6;
    __syncthreads();
    if((tid&63)==0){ red[wv]=mn; red[16+wv]=mx; }
    __syncthreads();
    mn=1e30f; mx=-1e30f;
    #pragma unroll
    for(int i=0;i<16;++i){ mn=fminf(mn,red[i]); mx=fmaxf(mx,red[16+i]); }
    float inv=1.0f/(mx-mn+1e-5f);
    #pragma unroll
    for(int s=0;s<4;++s) stout(out, 5160+(size_t)bk2*N_+tid+s*1024, (a[s]-mn)*inv, f);
    return;
  }
  int bk=blk, k=bk%K_, b=bk/K_;
  if(tid<64){
    float pm=pmax[((size_t)(b*64+tid))*5+k];
    float ps=psum[((size_t)(b*64+tid))*5+k];
    float M=pm;
    #pragma unroll
    for(int o=32;o>0;o>>=1) M=fmaxf(M,__shfl_xor(M,o,64));
    float fc=expf(pm-M);
    fch[tid]=fc;
    float e=ps*fc;
    #pragma unroll
    for(int o=32;o>0;o>>=1) e+=__shfl_xor(e,o,64);
    if(tid==0){ MSg[0]=M; MSg[1]=1.0f/e; }
  }
  __syncthreads();
  float Sinv=MSg[1];
  float ua=0;
  {
    int ch0=g*16;
    #pragma unroll 4
    for(int ci=0;ci<16;++ci){ int ch=ch0+ci; ua += fch[ch]*updpart[(((size_t)(b*64+ch))*5+k)*256+t]; }
  }
  part[g][0][t]=ua;
  if(t<4){
    float s=0;
    #pragma unroll 4
    for(int ci=0;ci<16;++ci){ int ch=g*16+ci; s += fch[ch]*sscp[(((size_t)(b*64+ch))*5+k)*4+t]; }
    part[g][1][t]=s;
  }
  __syncthreads();
  if(g==0 && t<4) cvec[t]=part[0][1][t]+part[1][1][t]+part[2][1][t]+part[3][1][t];
  __syncthreads();
  if(g==0){
    float uu=part[0][0][t]+part[1][0][t]+part[2][0][t]+part[3][0][t];
    u[t]=(uu+cvec[0]*Uvec[t]+cvec[1]*Uvec[256+t]+cvec[2]*Uvec[512+t]-cvec[3]*Uvec[768+t])*Sinv
         +Uvec[1024+t];
    h[t]=slot[bk*256+t];
  }
  __syncthreads();
  float p0=0,p1=0,p2=0,p3=0,p4=0,p5=0;
  int c0=g*64;
  #pragma unroll 8
  for(int cc=0;cc<64;++cc){
    int c=c0+cc;
    float uc=u[c], hc=h[c];
    const float* wi=WihT+(size_t)c*768+t;
    const float* wh=WhhT+(size_t)c*768+t;
    p0+=uc*wi[0]; p1+=uc*wi[256]; p2+=uc*wi[512];
    p3+=hc*wh[0]; p4+=hc*wh[256]; p5+=hc*wh[512];
  }
  part[g][0][t]=p0; part[g][1][t]=p1; part[g][2][t]=p2;
  part[g][3][t]=p3; part[g][4][t]=p4; part[g][5][t]=p5;
  __syncthreads();
  float hn=0;
  if(g==0){
    float gi0=ldin(bih,t,f)+part[0][0][t]+part[1][0][t]+part[2][0][t]+part[3][0][t];
    float gi1=ldin(bih,256+t,f)+part[0][1][t]+part[1][1][t]+part[2][1][t]+part[3][1][t];
    float gi2=ldin(bih,512+t,f)+part[0][2][t]+part[1][2][t]+part[2][2][t]+part[3][2][t];
    float gh0=ldin(bhh,t,f)+part[0][3][t]+part[1][3][t]+part[2][3][t]+part[3][3][t];
    float gh1=ldin(bhh,256+t,f)+part[0][4][t]+part[1][4][t]+part[2][4][t]+part[3][4][t];
    float gh2=ldin(bhh,512+t,f)+part[0][5][t]+part[1][5][t]+part[2][5][t]+part[3][5][t];
    float r=1.f/(1.f+expf(-(gi0+gh0)));
    float z=1.f/(1.f+expf(-(gi1+gh1)));
    float nn=tanhf(gi2+r*gh2);
    hn=(1.f-z)*nn+z*h[t];
  }
  float s=hn, sq=hn*hn, za=0, zb=0;
  breduce4_16(s,sq,za,zb,red);
  if(g==0){
    float m=s*(1.f/256.f), var=sq*(1.f/256.f)-m*m;
    u[t]=(hn-m)*rsqrtf(var+EPS_)*ldin(rg,t,f)+ldin(rb_,t,f);
  }
  __syncthreads();
  float pr=0;
  #pragma unroll 8
  for(int cc=0;cc<64;++cc){ int c=c0+cc; pr+=u[c]*WrT[(size_t)c*256+t]; }
  part[g][0][t]=pr;
  __syncthreads();
  if(g==0){
    float acc=ldin(rbias,t,f)+h[t]+part[0][0][t]+part[1][0][t]+part[2][0][t]+part[3][0][t];
    slot[bk*256+t]=acc;
    stout(out, (size_t)bk*256+t, acc, f);
    sn[t]=acc;
  }
  __syncthreads();
  float xs=(g==0)? sn[t]:0.f;
  float xq=xs*xs, zc=0, zd=0;
  breduce4_16(xs,xq,zc,zd,red);
  if(g==0){
    float m=xs*(1.f/256.f), var=xq*(1.f/256.f)-m*m;
    u[t]=(sn[t]-m)*rsqrtf(var+EPS_)*ldin(qg,t,f)+ldin(qb_,t,f);
  }
  __syncthreads();
  float pq=0;
  #pragma unroll 8
  for(int cc=0;cc<64;++cc){ int c=c0+cc; pq+=u[c]*WqT[(size_t)c*256+t]; }
  part[g][0][t]=pq;
  __syncthreads();
  if(g==0){
    float qv=part[0][0][t]+part[1][0][t]+part[2][0][t]+part[3][0][t];
    qbuf[bk*256+t]=qv;
  }
}

extern "C" void kernel_launch(void* const* d_in, const int* in_sizes, int n_in,
                              void* d_out, int out_size, void* d_ws, size_t ws_size,
                              hipStream_t stream)
{
  const void* feat =d_in[0];  const void* mask =d_in[1];  const void* noise=d_in[2];
  const void* mu   =d_in[3];  const void* lsig =d_in[4];  const void* ng   =d_in[5];
  const void* nb   =d_in[6];  const void* gW   =d_in[7];  const void* gb_  =d_in[8];
  const void* kW   =d_in[9];  const void* vW   =d_in[10]; const void* mg   =d_in[11];
  const void* mb_  =d_in[12]; const void* mW   =d_in[13]; const void* mbias=d_in[14];
  const void* qg   =d_in[15]; const void* qb_  =d_in[16]; const void* qW   =d_in[17];
  const void* Wih  =d_in[18]; const void* Whh  =d_in[19]; const void* bih  =d_in[20];
  const void* bhh  =d_in[21]; const void* rg   =d_in[22]; const void* rb_  =d_in[23];
  const void* rW   =d_in[24]; const void* rbias=d_in[25];

  char* p=(char*)d_ws;
  auto alloc=[&](size_t bytes)->char*{ char* r=p; p+=(bytes+255)&~(size_t)255; return r; };
  int*   flag   =(int*)  alloc(256);
  float* fg     =(float*)alloc(64);
  float* slot   =(float*)alloc(5120*4);
  float* qbuf   =(float*)alloc(5120*4);
  float* logits =(float*)alloc((size_t)81920*4);
  float* pmax   =(float*)alloc(1280*4);
  float* psum   =(float*)alloc(1280*4);
  float* updpart=(float*)alloc((size_t)256*5*256*4);
  float* sscp   =(float*)alloc((size_t)256*5*4*4);
  float* WqT    =(float*)alloc((size_t)65536*4);
  float* WrT    =(float*)alloc((size_t)65536*4);
  float* WihT   =(float*)alloc((size_t)196608*4);
  float* WhhT   =(float*)alloc((size_t)196608*4);
  float* gvec   =(float*)alloc(768*4);
  float* Uvec   =(float*)alloc(1280*4);
  float* Qs     =(float*)alloc(64);
  float* scal   =(float*)alloc((size_t)163840*4);
  u16*   Wkb    =(u16*)  alloc((size_t)65536*2);
  u16*   Wvb    =(u16*)  alloc((size_t)65536*2);
  u16*   Wgb    =(u16*)  alloc((size_t)65536*2);
  u16*   PkT    =(u16*)  alloc((size_t)16384*256*2);
  u16*   Pvb    =(u16*)  alloc((size_t)16384*256*2);

  prep1_kernel<<<PREP_N+6,256,0,stream>>>(feat,kW,vW,mW,qW,rW,Wih,Whh,mu,lsig,noise,gW,gb_,mg,
                                          mb_,mbias,mask,
                                          flag,WqT,WrT,WihT,WhhT,slot,gvec,Wkb,Wvb,Wgb,
                                          Uvec,Qs,fg,d_out);
  base_kernel<<<1044,256,0,stream>>>(flag,feat,ng,nb,Wkb,Wvb,Wgb,gvec,scal,PkT,Pvb,
                                     slot,qg,qb_,WqT,qbuf);
  for(int it=0; it<IT_; ++it){
    attn_kernel<<<B_*64,512,0,stream>>>(flag,qbuf,PkT,scal,Qs,Uvec,fg,mask,Pvb,
                                        logits,pmax,psum,updpart,sscp,(it==IT_-1)?1:0);
    int nb_g = (it==IT_-1)? 40 : 20;
    gru_kernel<<<nb_g,1024,0,stream>>>(flag,slot,updpart,sscp,Uvec,pmax,psum,logits,
                                       WihT,WhhT,bih,bhh,rg,rb_,WrT,rbias,
                                       qg,qb_,WqT,qbuf,(it==IT_-1)?1:0,d_out);
  }
}